// Round 1
// baseline (627.803 us; speedup 1.0000x reference)
//
#include <hip/hip_runtime.h>
#include <math.h>

#define DIN   256
#define DEMB  128
#define NCB   4
#define MCODES 512
#define NCODE 2048   // NCB * MCODES

// ---------------------------------------------------------------------------
// Kernel 1: L2-normalize each codebook row, store TRANSPOSED: cbnT[k][code].
// One 64-lane wave per code row. ~2 us total.
// ---------------------------------------------------------------------------
__global__ void normalize_codebook_kernel(const float* __restrict__ cb,
                                          float* __restrict__ cbnT) {
    const int code = blockIdx.x;     // 0..2047
    const int lane = threadIdx.x;    // 0..63
    const float2 v = reinterpret_cast<const float2*>(cb + (size_t)code * DEMB)[lane];
    float ss = v.x * v.x + v.y * v.y;
#pragma unroll
    for (int m = 1; m < 64; m <<= 1) ss += __shfl_xor(ss, m, 64);
    const float invn = 1.0f / sqrtf(ss);
    cbnT[(size_t)(2 * lane)     * NCODE + code] = v.x * invn;
    cbnT[(size_t)(2 * lane + 1) * NCODE + code] = v.y * invn;
}

// ---------------------------------------------------------------------------
// Kernel 2: fused project + cosine-sim + per-codebook argmax.
// 256 threads = 8 row-groups (ty) x 32 code-groups (tx). 64 rows per block.
// Thread micro-tile: 8 rows x 8 codes, K unrolled by 4 -> 256 fma / 16 loads.
// x-normalization skipped (argmax invariant to positive row scale).
// ---------------------------------------------------------------------------
__global__ __launch_bounds__(256) void fused_quantize_kernel(
        const float* __restrict__ inp,
        const float* __restrict__ proj,
        const float* __restrict__ cbnT,
        int* __restrict__ out) {
    __shared__ float sX[64][DEMB];          // 32 KB
    const int tid = threadIdx.x;
    const int tx  = tid & 31;               // code-group / dim-group
    const int ty  = tid >> 5;               // row-group (0..7)
    const int rowBase = blockIdx.x * 64;

    // ---- Phase 1: x = inp @ proj. Thread owns rows ty+8i, dims tx*4..tx*4+3.
    float acc1[8][4];
#pragma unroll
    for (int i = 0; i < 8; ++i)
#pragma unroll
        for (int j = 0; j < 4; ++j) acc1[i][j] = 0.0f;

#pragma unroll 1
    for (int k = 0; k < DIN; k += 4) {
        float4 pj[4];
#pragma unroll
        for (int j = 0; j < 4; ++j)
            pj[j] = *reinterpret_cast<const float4*>(proj + (size_t)(k + j) * DEMB + tx * 4);
#pragma unroll
        for (int i = 0; i < 8; ++i) {
            const int r = rowBase + ty + 8 * i;
            const float4 iv = *reinterpret_cast<const float4*>(inp + (size_t)r * DIN + k);
            const float* ivp = &iv.x;
#pragma unroll
            for (int j = 0; j < 4; ++j) {
                acc1[i][0] = fmaf(ivp[j], pj[j].x, acc1[i][0]);
                acc1[i][1] = fmaf(ivp[j], pj[j].y, acc1[i][1]);
                acc1[i][2] = fmaf(ivp[j], pj[j].z, acc1[i][2]);
                acc1[i][3] = fmaf(ivp[j], pj[j].w, acc1[i][3]);
            }
        }
    }
#pragma unroll
    for (int i = 0; i < 8; ++i) {
        *reinterpret_cast<float4*>(&sX[ty + 8 * i][tx * 4]) =
            make_float4(acc1[i][0], acc1[i][1], acc1[i][2], acc1[i][3]);
    }
    __syncthreads();

    // ---- Phase 2: similarity + argmax. Thread owns codes tx*8..tx*8+7 of each
    //      256-code chunk; 2 chunks per codebook.
    const int codeCol = tx * 8;
#pragma unroll 1
    for (int c = 0; c < NCB; ++c) {
        float bestv[8];
        int   besti[8];
#pragma unroll
        for (int i = 0; i < 8; ++i) { bestv[i] = -INFINITY; besti[i] = 0; }

#pragma unroll 1
        for (int half = 0; half < 2; ++half) {
            const int base = c * MCODES + half * 256;   // global code base of chunk
            float acc[8][8];
#pragma unroll
            for (int i = 0; i < 8; ++i)
#pragma unroll
                for (int j = 0; j < 8; ++j) acc[i][j] = 0.0f;

#pragma unroll 1
            for (int k = 0; k < DEMB; k += 4) {
                float4 cv0[4], cv1[4];
#pragma unroll
                for (int j = 0; j < 4; ++j) {
                    const float* p = cbnT + (size_t)(k + j) * NCODE + base + codeCol;
                    cv0[j] = reinterpret_cast<const float4*>(p)[0];
                    cv1[j] = reinterpret_cast<const float4*>(p)[1];
                }
#pragma unroll
                for (int i = 0; i < 8; ++i) {
                    const float4 rv = *reinterpret_cast<const float4*>(&sX[ty + 8 * i][k]);
                    const float* rvp = &rv.x;
#pragma unroll
                    for (int j = 0; j < 4; ++j) {
                        acc[i][0] = fmaf(rvp[j], cv0[j].x, acc[i][0]);
                        acc[i][1] = fmaf(rvp[j], cv0[j].y, acc[i][1]);
                        acc[i][2] = fmaf(rvp[j], cv0[j].z, acc[i][2]);
                        acc[i][3] = fmaf(rvp[j], cv0[j].w, acc[i][3]);
                        acc[i][4] = fmaf(rvp[j], cv1[j].x, acc[i][4]);
                        acc[i][5] = fmaf(rvp[j], cv1[j].y, acc[i][5]);
                        acc[i][6] = fmaf(rvp[j], cv1[j].z, acc[i][6]);
                        acc[i][7] = fmaf(rvp[j], cv1[j].w, acc[i][7]);
                    }
                }
            }
            // running argmax update (ascending gidx; strict > keeps first max,
            // matching jnp.argmax tie semantics)
#pragma unroll
            for (int cc = 0; cc < 8; ++cc) {
                const int gidx = base + codeCol + cc;
#pragma unroll
                for (int i = 0; i < 8; ++i) {
                    if (acc[i][cc] > bestv[i]) { bestv[i] = acc[i][cc]; besti[i] = gidx; }
                }
            }
        }

        // cross-lane reduce over the 32 code-group lanes (butterfly; prefer
        // lower index on exact ties)
#pragma unroll
        for (int m = 1; m < 32; m <<= 1) {
#pragma unroll
            for (int i = 0; i < 8; ++i) {
                const float ov = __shfl_xor(bestv[i], m, 64);
                const int   oi = __shfl_xor(besti[i], m, 64);
                if (ov > bestv[i] || (ov == bestv[i] && oi < besti[i])) {
                    bestv[i] = ov; besti[i] = oi;
                }
            }
        }
        if (tx == 0) {
#pragma unroll
            for (int i = 0; i < 8; ++i)
                out[(size_t)(rowBase + ty + 8 * i) * NCB + c] = besti[i] - c * MCODES;
        }
    }
}

// ---------------------------------------------------------------------------
extern "C" void kernel_launch(void* const* d_in, const int* in_sizes, int n_in,
                              void* d_out, int out_size, void* d_ws, size_t ws_size,
                              hipStream_t stream) {
    const float* inp  = (const float*)d_in[0];   // [8,16,512,256]
    const float* proj = (const float*)d_in[1];   // [256,128]
    const float* cb   = (const float*)d_in[2];   // [4,512,128]
    int*   out  = (int*)d_out;                   // [8,16,512,4] int32
    float* cbnT = (float*)d_ws;                  // [128][2048] = 1 MB

    hipLaunchKernelGGL(normalize_codebook_kernel, dim3(NCODE), dim3(64), 0, stream,
                       cb, cbnT);
    hipLaunchKernelGGL(fused_quantize_kernel, dim3(65536 / 64), dim3(256), 0, stream,
                       inp, proj, cbnT, out);
}

// Round 2
// 510.551 us; speedup vs baseline: 1.2297x; 1.2297x over previous
//
#include <hip/hip_runtime.h>
#include <math.h>

#define DIN   256
#define DEMB  128
#define NCB   4
#define MCODES 512
#define NCODE 2048   // NCB * MCODES

static __device__ __forceinline__ float4 ld4(const float* p) {
    return *reinterpret_cast<const float4*>(p);
}

// ---------------------------------------------------------------------------
// Kernel 1: L2-normalize each codebook row, store TRANSPOSED: cbnT[k][code].
// ---------------------------------------------------------------------------
__global__ void normalize_codebook_kernel(const float* __restrict__ cb,
                                          float* __restrict__ cbnT) {
    const int code = blockIdx.x;     // 0..2047
    const int lane = threadIdx.x;    // 0..63
    const float2 v = reinterpret_cast<const float2*>(cb + (size_t)code * DEMB)[lane];
    float ss = v.x * v.x + v.y * v.y;
#pragma unroll
    for (int m = 1; m < 64; m <<= 1) ss += __shfl_xor(ss, m, 64);
    const float invn = 1.0f / sqrtf(ss);
    cbnT[(size_t)(2 * lane)     * NCODE + code] = v.x * invn;
    cbnT[(size_t)(2 * lane + 1) * NCODE + code] = v.y * invn;
}

// ---------------------------------------------------------------------------
// Kernel 2: fused project + cosine-sim + per-codebook argmax.
// 256 threads = 8 row-groups (ty) x 32 code-groups (tx). 64 rows per block.
// Register ping-pong double-buffering in both k-loops: prefetch step k+4
// while FMA-ing step k (hides ~250cy L2 latency inside one wave).
// x-normalization skipped (argmax invariant to positive row scale).
// ---------------------------------------------------------------------------
__global__ __launch_bounds__(256) void fused_quantize_kernel(
        const float* __restrict__ inp,
        const float* __restrict__ proj,
        const float* __restrict__ cbnT,
        int* __restrict__ out) {
    __shared__ float sX[64][DEMB];          // 32 KB
    const int tid = threadIdx.x;
    const int tx  = tid & 31;               // code-group / dim-group
    const int ty  = tid >> 5;               // row-group (0..7)
    const int rowBase = blockIdx.x * 64;

    // ---- Phase 1: x = inp @ proj. Thread owns rows ty+8i, dims tx*4..tx*4+3.
    {
        float acc1[8][4];
#pragma unroll
        for (int i = 0; i < 8; ++i)
#pragma unroll
            for (int j = 0; j < 4; ++j) acc1[i][j] = 0.0f;

        const float* inRow0 = inp + (size_t)(rowBase + ty) * DIN;   // row stride 8*DIN between i
        const float* pjCol  = proj + tx * 4;

        float4 ivA[8], ivB[8], pjA[4], pjB[4];
        auto load_step = [&](float4 iv[8], float4 pj[4], int kk) {
#pragma unroll
            for (int j = 0; j < 4; ++j)
                pj[j] = ld4(pjCol + (size_t)(kk + j) * DEMB);
#pragma unroll
            for (int i = 0; i < 8; ++i)
                iv[i] = ld4(inRow0 + (size_t)(8 * i) * DIN + kk);
        };
        auto fma_step = [&](const float4 iv[8], const float4 pj[4]) {
#pragma unroll
            for (int i = 0; i < 8; ++i) {
                const float* ivp = reinterpret_cast<const float*>(&iv[i]);
#pragma unroll
                for (int j = 0; j < 4; ++j) {
                    acc1[i][0] = fmaf(ivp[j], pj[j].x, acc1[i][0]);
                    acc1[i][1] = fmaf(ivp[j], pj[j].y, acc1[i][1]);
                    acc1[i][2] = fmaf(ivp[j], pj[j].z, acc1[i][2]);
                    acc1[i][3] = fmaf(ivp[j], pj[j].w, acc1[i][3]);
                }
            }
        };

        load_step(ivA, pjA, 0);
#pragma unroll 1
        for (int k = 0; k < DIN; k += 8) {
            load_step(ivB, pjB, k + 4);
            fma_step(ivA, pjA);
            if (k + 8 < DIN) load_step(ivA, pjA, k + 8);
            fma_step(ivB, pjB);
        }
#pragma unroll
        for (int i = 0; i < 8; ++i) {
            *reinterpret_cast<float4*>(&sX[ty + 8 * i][tx * 4]) =
                make_float4(acc1[i][0], acc1[i][1], acc1[i][2], acc1[i][3]);
        }
    }
    __syncthreads();

    // ---- Phase 2: similarity + argmax. Thread owns codes tx*8..tx*8+7 of each
    //      256-code chunk; 2 chunks per codebook.
    const int codeCol = tx * 8;
#pragma unroll 1
    for (int c = 0; c < NCB; ++c) {
        float bestv[8];
        int   besti[8];
#pragma unroll
        for (int i = 0; i < 8; ++i) { bestv[i] = -INFINITY; besti[i] = 0; }

#pragma unroll 1
        for (int half = 0; half < 2; ++half) {
            const int base = c * MCODES + half * 256;   // global code base of chunk
            const float* cbBase = cbnT + base + codeCol;
            float acc[8][8];
#pragma unroll
            for (int i = 0; i < 8; ++i)
#pragma unroll
                for (int j = 0; j < 8; ++j) acc[i][j] = 0.0f;

            float4 a0[4], a1[4], b0[4], b1[4];
            auto load_cv = [&](float4 c0[4], float4 c1[4], int kk) {
#pragma unroll
                for (int j = 0; j < 4; ++j) {
                    const float* p = cbBase + (size_t)(kk + j) * NCODE;
                    c0[j] = ld4(p);
                    c1[j] = ld4(p + 4);
                }
            };
            auto fma_cv = [&](const float4 c0[4], const float4 c1[4], int kk) {
#pragma unroll
                for (int i = 0; i < 8; ++i) {
                    const float4 rv = ld4(&sX[ty + 8 * i][kk]);
                    const float* rvp = reinterpret_cast<const float*>(&rv);
#pragma unroll
                    for (int j = 0; j < 4; ++j) {
                        acc[i][0] = fmaf(rvp[j], c0[j].x, acc[i][0]);
                        acc[i][1] = fmaf(rvp[j], c0[j].y, acc[i][1]);
                        acc[i][2] = fmaf(rvp[j], c0[j].z, acc[i][2]);
                        acc[i][3] = fmaf(rvp[j], c0[j].w, acc[i][3]);
                        acc[i][4] = fmaf(rvp[j], c1[j].x, acc[i][4]);
                        acc[i][5] = fmaf(rvp[j], c1[j].y, acc[i][5]);
                        acc[i][6] = fmaf(rvp[j], c1[j].z, acc[i][6]);
                        acc[i][7] = fmaf(rvp[j], c1[j].w, acc[i][7]);
                    }
                }
            };

            load_cv(a0, a1, 0);
#pragma unroll 1
            for (int k = 0; k < DEMB; k += 8) {
                load_cv(b0, b1, k + 4);
                fma_cv(a0, a1, k);
                if (k + 8 < DEMB) load_cv(a0, a1, k + 8);
                fma_cv(b0, b1, k + 4);
            }

            // running argmax update (ascending gidx; strict > keeps first max,
            // matching jnp.argmax tie semantics)
#pragma unroll
            for (int cc = 0; cc < 8; ++cc) {
                const int gidx = base + codeCol + cc;
#pragma unroll
                for (int i = 0; i < 8; ++i) {
                    if (acc[i][cc] > bestv[i]) { bestv[i] = acc[i][cc]; besti[i] = gidx; }
                }
            }
        }

        // cross-lane reduce over the 32 code-group lanes (butterfly; prefer
        // lower index on exact ties)
#pragma unroll
        for (int m = 1; m < 32; m <<= 1) {
#pragma unroll
            for (int i = 0; i < 8; ++i) {
                const float ov = __shfl_xor(bestv[i], m, 64);
                const int   oi = __shfl_xor(besti[i], m, 64);
                if (ov > bestv[i] || (ov == bestv[i] && oi < besti[i])) {
                    bestv[i] = ov; besti[i] = oi;
                }
            }
        }
        if (tx == 0) {
#pragma unroll
            for (int i = 0; i < 8; ++i)
                out[(size_t)(rowBase + ty + 8 * i) * NCB + c] = besti[i] - c * MCODES;
        }
    }
}

// ---------------------------------------------------------------------------
extern "C" void kernel_launch(void* const* d_in, const int* in_sizes, int n_in,
                              void* d_out, int out_size, void* d_ws, size_t ws_size,
                              hipStream_t stream) {
    const float* inp  = (const float*)d_in[0];   // [8,16,512,256]
    const float* proj = (const float*)d_in[1];   // [256,128]
    const float* cb   = (const float*)d_in[2];   // [4,512,128]
    int*   out  = (int*)d_out;                   // [8,16,512,4] int32
    float* cbnT = (float*)d_ws;                  // [128][2048] = 1 MB

    hipLaunchKernelGGL(normalize_codebook_kernel, dim3(NCODE), dim3(64), 0, stream,
                       cb, cbnT);
    hipLaunchKernelGGL(fused_quantize_kernel, dim3(65536 / 64), dim3(256), 0, stream,
                       inp, proj, cbnT, out);
}

// Round 3
// 357.620 us; speedup vs baseline: 1.7555x; 1.4276x over previous
//
#include <hip/hip_runtime.h>
#include <math.h>

#define DIN    256
#define DEMB   128
#define NCB    4
#define MCODES 512
#define NCODE  2048
#define RPB    128          // rows per block
#define MARGIN 1.5e-4f      // >10x rigorous split-bf16 error bound (~1.3e-5)

using bf16x8 = __attribute__((ext_vector_type(8))) short;
using f32x16 = __attribute__((ext_vector_type(16))) float;

static __device__ __forceinline__ unsigned short f2bf(float f) {   // RNE f32->bf16
    unsigned u = __float_as_uint(f);
    u += 0x7FFFu + ((u >> 16) & 1u);
    return (unsigned short)(u >> 16);
}
static __device__ __forceinline__ float bf2f(unsigned short h) {
    return __uint_as_float(((unsigned)h) << 16);
}
static __device__ __forceinline__ float4 ld4(const float* p) {
    return *reinterpret_cast<const float4*>(p);
}

// ---------------------------------------------------------------------------
// Kernel 1: normalize codebook rows; emit (a) f32 copy for exact stage-B,
// (b) hi/lo bf16 split laid out in mfma_32x32x16 A-fragment order:
//    ushort index = ((ct*1024 + kt*128 + hl*64 + g*32 + codeIn)*8 + i)
// where code k: kt=k>>4, g=(k>>3)&1, i=k&7;  phase-2 lane = g*32+codeIn.
// ---------------------------------------------------------------------------
__global__ __launch_bounds__(256) void prep_codebook(
        const float* __restrict__ cb, float* __restrict__ cbn,
        unsigned short* __restrict__ cbA) {
    const int w = threadIdx.x >> 6, lane = threadIdx.x & 63;
    const int code = blockIdx.x * 4 + w;                 // 0..2047
    const float2 v = reinterpret_cast<const float2*>(cb + (size_t)code * DEMB)[lane];
    float ss = v.x * v.x + v.y * v.y;
#pragma unroll
    for (int m = 1; m < 64; m <<= 1) ss += __shfl_xor(ss, m, 64);
    const float rn = 1.0f / sqrtf(ss);
    const float x0 = v.x * rn, x1 = v.y * rn;
    reinterpret_cast<float2*>(cbn + (size_t)code * DEMB)[lane] = make_float2(x0, x1);

    const unsigned short h0 = f2bf(x0), h1 = f2bf(x1);
    const unsigned short l0 = f2bf(x0 - bf2f(h0)), l1 = f2bf(x1 - bf2f(h1));
    const int ct = code >> 5, ci = code & 31;
    const int kt = lane >> 3, g = (lane >> 2) & 1, i = 2 * (lane & 3);
    const size_t base = ((size_t)ct * 1024 + kt * 128 + g * 32 + ci) * 8 + i;
    *reinterpret_cast<ushort2*>(cbA + base)       = make_ushort2(h0, h1);  // hi (hl=0)
    *reinterpret_cast<ushort2*>(cbA + base + 512) = make_ushort2(l0, l1);  // lo (hl=1)
}

// ---------------------------------------------------------------------------
// Kernel 2: project (f32 VALU) -> split-bf16 MFMA similarity -> argmax with
// margin-certified exactness; rare exact-f32 inline recheck.
// 256 threads = 4 waves; 128 rows/block; wave owns a 32-row MFMA B-tile.
// ---------------------------------------------------------------------------
__global__ __launch_bounds__(256) void fused_quantize_kernel(
        const float* __restrict__ inp, const float* __restrict__ proj,
        const float* __restrict__ cbn, const unsigned short* __restrict__ cbA,
        int* __restrict__ out) {
    __shared__ float sX[RPB][132];     // unnormalized f32 x (exact, for stage B)
    __shared__ float sRn[RPB];         // 1/||x|| per row
    const int tid = threadIdx.x;
    const int tx = tid & 31, ty = tid >> 5;
    const int rowBase = blockIdx.x * RPB;

    // ---- Phase 1: x = inp @ proj (pipelined f32), 2 passes of 64 rows.
#pragma unroll 1
    for (int p = 0; p < 2; ++p) {
        float acc1[8][4];
#pragma unroll
        for (int i = 0; i < 8; ++i)
#pragma unroll
            for (int j = 0; j < 4; ++j) acc1[i][j] = 0.0f;

        const float* inRow0 = inp + (size_t)(rowBase + p * 64 + ty) * DIN;
        const float* pjCol  = proj + tx * 4;

        float4 ivA[8], ivB[8], pjA[4], pjB[4];
        auto load_step = [&](float4 iv[8], float4 pj[4], int kk) {
#pragma unroll
            for (int j = 0; j < 4; ++j) pj[j] = ld4(pjCol + (size_t)(kk + j) * DEMB);
#pragma unroll
            for (int i = 0; i < 8; ++i) iv[i] = ld4(inRow0 + (size_t)(8 * i) * DIN + kk);
        };
        auto fma_step = [&](const float4 iv[8], const float4 pj[4]) {
#pragma unroll
            for (int i = 0; i < 8; ++i) {
                const float* ivp = reinterpret_cast<const float*>(&iv[i]);
#pragma unroll
                for (int j = 0; j < 4; ++j) {
                    acc1[i][0] = fmaf(ivp[j], pj[j].x, acc1[i][0]);
                    acc1[i][1] = fmaf(ivp[j], pj[j].y, acc1[i][1]);
                    acc1[i][2] = fmaf(ivp[j], pj[j].z, acc1[i][2]);
                    acc1[i][3] = fmaf(ivp[j], pj[j].w, acc1[i][3]);
                }
            }
        };
        load_step(ivA, pjA, 0);
#pragma unroll 1
        for (int k = 0; k < DIN; k += 8) {
            load_step(ivB, pjB, k + 4);
            fma_step(ivA, pjA);
            if (k + 8 < DIN) load_step(ivA, pjA, k + 8);
            fma_step(ivB, pjB);
        }
#pragma unroll
        for (int i = 0; i < 8; ++i) {
            const int r = p * 64 + ty + 8 * i;
            float ss = acc1[i][0] * acc1[i][0] + acc1[i][1] * acc1[i][1] +
                       acc1[i][2] * acc1[i][2] + acc1[i][3] * acc1[i][3];
#pragma unroll
            for (int mm = 1; mm < 32; mm <<= 1) ss += __shfl_xor(ss, mm, 64);
            if (tx == 0) sRn[r] = 1.0f / sqrtf(ss);
            *reinterpret_cast<float4*>(&sX[r][tx * 4]) =
                make_float4(acc1[i][0], acc1[i][1], acc1[i][2], acc1[i][3]);
        }
    }
    __syncthreads();

    // ---- Phase 2: MFMA similarity + argmax.
    const int lane = tid & 63, wv = tid >> 6;
    const int kg = lane >> 5;                 // k-group within fragment
    const int rowL = wv * 32 + (lane & 31);   // this lane's x-row (B col n)

    // Hoist B fragments (this wave's 32 rows), split hi/lo: 8 ksteps.
    bf16x8 Bhi[8], Blo[8];
    {
        const float rn = sRn[rowL];
#pragma unroll
        for (int kt = 0; kt < 8; ++kt) {
            const int k0 = kt * 16 + kg * 8;
            float4 f0 = ld4(&sX[rowL][k0]);
            float4 f1 = ld4(&sX[rowL][k0 + 4]);
            float xs[8] = {f0.x, f0.y, f0.z, f0.w, f1.x, f1.y, f1.z, f1.w};
            bf16x8 hv, lv;
#pragma unroll
            for (int e = 0; e < 8; ++e) {
                const float xn = xs[e] * rn;
                const unsigned short h = f2bf(xn);
                hv[e] = (short)h;
                lv[e] = (short)f2bf(xn - bf2f(h));
            }
            Bhi[kt] = hv; Blo[kt] = lv;
        }
    }

    float t1 = -INFINITY, t2 = -INFINITY; int i1 = 0;
    const short* pA = reinterpret_cast<const short*>(cbA) + (size_t)lane * 8;

#pragma unroll 1
    for (int ct = 0; ct < 64; ++ct) {
        if ((ct & 1) == 0) __syncthreads();   // keep waves' A-streams L1-resident
        const short* pct = pA + (size_t)ct * 8192;

        f32x16 accA, accB;
#pragma unroll
        for (int r = 0; r < 16; ++r) { accA[r] = 0.0f; accB[r] = 0.0f; }
#pragma unroll
        for (int kt = 0; kt < 8; ++kt) {
            const bf16x8 Ahi = *reinterpret_cast<const bf16x8*>(pct + kt * 1024);
            const bf16x8 Alo = *reinterpret_cast<const bf16x8*>(pct + kt * 1024 + 512);
            accA = __builtin_amdgcn_mfma_f32_32x32x16_bf16(Ahi, Bhi[kt], accA, 0, 0, 0);
            accB = __builtin_amdgcn_mfma_f32_32x32x16_bf16(Ahi, Blo[kt], accB, 0, 0, 0);
            accB = __builtin_amdgcn_mfma_f32_32x32x16_bf16(Alo, Bhi[kt], accB, 0, 0, 0);
        }
        // running top1/top2/idx (codes m ascend within lane => first-max kept)
#pragma unroll
        for (int r = 0; r < 16; ++r) {
            const float v = accA[r] + accB[r];
            const int gidx = ct * 32 + ((r & 3) + 8 * (r >> 2) + 4 * kg);
            t2 = fmaxf(t2, fminf(v, t1));
            if (v > t1) { t1 = v; i1 = gidx; }
        }

        if ((ct & 15) == 15) {                 // codebook boundary
            const int cb = ct >> 4;
            const float o1 = __shfl_xor(t1, 32, 64);
            const float o2 = __shfl_xor(t2, 32, 64);
            const int   oi = __shfl_xor(i1, 32, 64);
            const float m2 = fmaxf(fmaxf(t2, o2), fminf(t1, o1));
            if (o1 > t1 || (o1 == t1 && oi < i1)) { t1 = o1; i1 = oi; }
            const bool unc = (t1 - m2) < MARGIN;
            if (lane < 32 && !unc)
                out[(size_t)(rowBase + rowL) * NCB + cb] = i1 - cb * MCODES;

            unsigned long long msk = __ballot(unc && lane < 32);
            while (msk) {                      // rare exact-f32 recheck
                const int r = __ffsll((unsigned long long)msk) - 1; msk &= msk - 1;
                const int rl = wv * 32 + r;
                float best = -INFINITY; int bi = 0;
#pragma unroll 1
                for (int j = 0; j < 8; ++j) {
                    const int c = lane + 64 * j;
                    const float* cv = cbn + ((size_t)cb * MCODES + c) * DEMB;
                    float s0 = 0, s1 = 0, s2 = 0, s3 = 0;
#pragma unroll
                    for (int k = 0; k < DEMB; k += 4) {
                        const float4 xk = ld4(&sX[rl][k]);
                        const float4 ck = ld4(&cv[k]);
                        s0 = fmaf(xk.x, ck.x, s0); s1 = fmaf(xk.y, ck.y, s1);
                        s2 = fmaf(xk.z, ck.z, s2); s3 = fmaf(xk.w, ck.w, s3);
                    }
                    const float s = (s0 + s1) + (s2 + s3);
                    if (s > best) { best = s; bi = c; }
                }
#pragma unroll
                for (int mm = 1; mm < 64; mm <<= 1) {
                    const float ov = __shfl_xor(best, mm, 64);
                    const int   oc = __shfl_xor(bi, mm, 64);
                    if (ov > best || (ov == best && oc < bi)) { best = ov; bi = oc; }
                }
                if (lane == 0) out[(size_t)(rowBase + rl) * NCB + cb] = bi;
            }
            t1 = -INFINITY; t2 = -INFINITY; i1 = 0;
        }
    }
}

// ---------------------------------------------------------------------------
extern "C" void kernel_launch(void* const* d_in, const int* in_sizes, int n_in,
                              void* d_out, int out_size, void* d_ws, size_t ws_size,
                              hipStream_t stream) {
    const float* inp  = (const float*)d_in[0];   // [8,16,512,256]
    const float* proj = (const float*)d_in[1];   // [256,128]
    const float* cb   = (const float*)d_in[2];   // [4,512,128]
    int* out = (int*)d_out;                      // [8,16,512,4] int32

    float* cbn = (float*)d_ws;                                    // 1 MB f32
    unsigned short* cbA = (unsigned short*)((char*)d_ws + (1 << 20)); // 1 MB bf16 hi/lo

    hipLaunchKernelGGL(prep_codebook, dim3(NCODE / 4), dim3(256), 0, stream,
                       cb, cbn, cbA);
    hipLaunchKernelGGL(fused_quantize_kernel, dim3(65536 / RPB), dim3(256), 0, stream,
                       inp, proj, cbn, cbA, out);
}

// Round 4
// 330.172 us; speedup vs baseline: 1.9014x; 1.0831x over previous
//
#include <hip/hip_runtime.h>
#include <math.h>

#define DIN    256
#define DEMB   128
#define NCB    4
#define MCODES 512
#define NCODE  2048
#define MARGIN 1.5e-4f      // >10x rigorous split-bf16 error bound (~1.3e-5)

using bf16x8 = __attribute__((ext_vector_type(8))) short;
using f32x16 = __attribute__((ext_vector_type(16))) float;

static __device__ __forceinline__ unsigned short f2bf(float f) {   // RNE f32->bf16
    unsigned u = __float_as_uint(f);
    u += 0x7FFFu + ((u >> 16) & 1u);
    return (unsigned short)(u >> 16);
}
static __device__ __forceinline__ float bf2f(unsigned short h) {
    return __uint_as_float(((unsigned)h) << 16);
}
static __device__ __forceinline__ float4 ld4(const float* p) {
    return *reinterpret_cast<const float4*>(p);
}
// async global->LDS DMA, 16B per lane, wave-uniform LDS base (guide §5)
static __device__ __forceinline__ void gload_lds16(const void* g, void* l) {
    __builtin_amdgcn_global_load_lds(
        (const __attribute__((address_space(1))) void*)g,
        (__attribute__((address_space(3))) void*)l, 16, 0, 0);
}

// ---------------------------------------------------------------------------
// Kernel 1: normalize codebook rows; emit (a) f32 copy for exact stage-B,
// (b) hi/lo bf16 split in mfma_32x32x16 A-fragment order (tile ct = 16 KB
// contiguous: [kt 0..8][hl 0..2][lane 0..64][8 shorts]).
// ---------------------------------------------------------------------------
__global__ __launch_bounds__(256) void prep_codebook(
        const float* __restrict__ cb, float* __restrict__ cbn,
        unsigned short* __restrict__ cbA) {
    const int w = threadIdx.x >> 6, lane = threadIdx.x & 63;
    const int code = blockIdx.x * 4 + w;                 // 0..2047
    const float2 v = reinterpret_cast<const float2*>(cb + (size_t)code * DEMB)[lane];
    float ss = v.x * v.x + v.y * v.y;
#pragma unroll
    for (int m = 1; m < 64; m <<= 1) ss += __shfl_xor(ss, m, 64);
    const float rn = 1.0f / sqrtf(ss);
    const float x0 = v.x * rn, x1 = v.y * rn;
    reinterpret_cast<float2*>(cbn + (size_t)code * DEMB)[lane] = make_float2(x0, x1);

    const unsigned short h0 = f2bf(x0), h1 = f2bf(x1);
    const unsigned short l0 = f2bf(x0 - bf2f(h0)), l1 = f2bf(x1 - bf2f(h1));
    const int ct = code >> 5, ci = code & 31;
    const int kt = lane >> 3, g = (lane >> 2) & 1, i = 2 * (lane & 3);
    const size_t base = ((size_t)ct * 1024 + kt * 128 + g * 32 + ci) * 8 + i;
    *reinterpret_cast<ushort2*>(cbA + base)       = make_ushort2(h0, h1);  // hi
    *reinterpret_cast<ushort2*>(cbA + base + 512) = make_ushort2(l0, l1);  // lo
}

// ---------------------------------------------------------------------------
// Kernel 2: projection x = inp @ proj (f32 VALU, register-pipelined).
// 64 rows/block, 1024 blocks. Writes x (f32) + 1/||x|| to workspace.
// No LDS -> occupancy limited only by VGPR (~3 waves/SIMD).
// ---------------------------------------------------------------------------
__global__ __launch_bounds__(256) void project_kernel(
        const float* __restrict__ inp, const float* __restrict__ proj,
        float* __restrict__ xw, float* __restrict__ rnw) {
    const int tid = threadIdx.x, tx = tid & 31, ty = tid >> 5;
    const int rowBase = blockIdx.x * 64;

    float acc1[8][4];
#pragma unroll
    for (int i = 0; i < 8; ++i)
#pragma unroll
        for (int j = 0; j < 4; ++j) acc1[i][j] = 0.0f;

    const float* inRow0 = inp + (size_t)(rowBase + ty) * DIN;
    const float* pjCol  = proj + tx * 4;

    float4 ivA[8], ivB[8], pjA[4], pjB[4];
    auto load_step = [&](float4 iv[8], float4 pj[4], int kk) {
#pragma unroll
        for (int j = 0; j < 4; ++j) pj[j] = ld4(pjCol + (size_t)(kk + j) * DEMB);
#pragma unroll
        for (int i = 0; i < 8; ++i) iv[i] = ld4(inRow0 + (size_t)(8 * i) * DIN + kk);
    };
    auto fma_step = [&](const float4 iv[8], const float4 pj[4]) {
#pragma unroll
        for (int i = 0; i < 8; ++i) {
            const float* ivp = reinterpret_cast<const float*>(&iv[i]);
#pragma unroll
            for (int j = 0; j < 4; ++j) {
                acc1[i][0] = fmaf(ivp[j], pj[j].x, acc1[i][0]);
                acc1[i][1] = fmaf(ivp[j], pj[j].y, acc1[i][1]);
                acc1[i][2] = fmaf(ivp[j], pj[j].z, acc1[i][2]);
                acc1[i][3] = fmaf(ivp[j], pj[j].w, acc1[i][3]);
            }
        }
    };
    load_step(ivA, pjA, 0);
#pragma unroll 1
    for (int k = 0; k < DIN; k += 8) {
        load_step(ivB, pjB, k + 4);
        fma_step(ivA, pjA);
        if (k + 8 < DIN) load_step(ivA, pjA, k + 8);
        fma_step(ivB, pjB);
    }
#pragma unroll
    for (int i = 0; i < 8; ++i) {
        const int r = rowBase + ty + 8 * i;
        float ss = acc1[i][0] * acc1[i][0] + acc1[i][1] * acc1[i][1] +
                   acc1[i][2] * acc1[i][2] + acc1[i][3] * acc1[i][3];
#pragma unroll
        for (int mm = 1; mm < 32; mm <<= 1) ss += __shfl_xor(ss, mm, 64);
        if (tx == 0) rnw[r] = 1.0f / sqrtf(ss);
        *reinterpret_cast<float4*>(xw + (size_t)r * DEMB + tx * 4) =
            make_float4(acc1[i][0], acc1[i][1], acc1[i][2], acc1[i][3]);
    }
}

// ---------------------------------------------------------------------------
// Kernel 3: similarity + argmax. 128 rows/block, 4 waves x 32 rows.
// A-tiles double-buffered in LDS via global_load_lds; counted vmcnt(4)
// (T3/T4 pattern: loads stay in flight across the barrier, never drain
// to 0 mid-loop). B fragments (split-bf16 normalized x) hoisted in VGPRs.
// ---------------------------------------------------------------------------
__global__ __launch_bounds__(256) void sim_kernel(
        const float* __restrict__ xw, const float* __restrict__ rnw,
        const unsigned short* __restrict__ cbA, const float* __restrict__ cbn,
        int* __restrict__ out) {
    __shared__ __align__(16) short sA[2][8192];   // 2 x 16 KB A-tile buffers
    const int tid = threadIdx.x;
    const int lane = tid & 63, wv = tid >> 6;
    const int kg = lane >> 5;
    const int row = blockIdx.x * 128 + wv * 32 + (lane & 31);

    auto stage = [&](int bi, int ct) {    // 4 x 16B DMA per thread = 16 KB/block
        const short* g = (const short*)cbA + (size_t)ct * 8192 + wv * 512 + lane * 8;
        short* l = &sA[bi][wv * 512];
#pragma unroll
        for (int r = 0; r < 4; ++r)
            gload_lds16(g + r * 2048, l + r * 2048);
    };

    stage(0, 0);

    // Hoist B fragments: normalize + split hi/lo this lane's x row.
    bf16x8 Bhi[8], Blo[8];
    {
        const float rn = rnw[row];
        const float* xr = xw + (size_t)row * DEMB;
#pragma unroll
        for (int kt = 0; kt < 8; ++kt) {
            const float4 f0 = ld4(xr + kt * 16 + kg * 8);
            const float4 f1 = ld4(xr + kt * 16 + kg * 8 + 4);
            const float xs[8] = {f0.x, f0.y, f0.z, f0.w, f1.x, f1.y, f1.z, f1.w};
            bf16x8 hv, lv;
#pragma unroll
            for (int e = 0; e < 8; ++e) {
                const float xn = xs[e] * rn;
                const unsigned short h = f2bf(xn);
                hv[e] = (short)h;
                lv[e] = (short)f2bf(xn - bf2f(h));
            }
            Bhi[kt] = hv; Blo[kt] = lv;
        }
    }

    float t1 = -INFINITY, t2 = -INFINITY; int i1 = 0;

#pragma unroll 1
    for (int ct = 0; ct < 64; ++ct) {
        const int bi = ct & 1;
        if (ct + 1 < 64) {
            stage(bi ^ 1, ct + 1);
            asm volatile("s_waitcnt vmcnt(4)" ::: "memory");  // buf[bi] ready, next 4 in flight
        } else {
            asm volatile("s_waitcnt vmcnt(0)" ::: "memory");
        }
        __builtin_amdgcn_s_barrier();
        asm volatile("" ::: "memory");

        f32x16 accA, accB;
#pragma unroll
        for (int r = 0; r < 16; ++r) { accA[r] = 0.0f; accB[r] = 0.0f; }
        const short* pa = &sA[bi][lane * 8];
#pragma unroll
        for (int kt = 0; kt < 8; ++kt) {
            const bf16x8 Ahi = *reinterpret_cast<const bf16x8*>(pa + kt * 1024);
            const bf16x8 Alo = *reinterpret_cast<const bf16x8*>(pa + kt * 1024 + 512);
            accA = __builtin_amdgcn_mfma_f32_32x32x16_bf16(Ahi, Bhi[kt], accA, 0, 0, 0);
            accB = __builtin_amdgcn_mfma_f32_32x32x16_bf16(Ahi, Blo[kt], accB, 0, 0, 0);
            accB = __builtin_amdgcn_mfma_f32_32x32x16_bf16(Alo, Bhi[kt], accB, 0, 0, 0);
        }
#pragma unroll
        for (int r = 0; r < 16; ++r) {
            const float v = accA[r] + accB[r];
            const int gidx = ct * 32 + ((r & 3) + 8 * (r >> 2) + 4 * kg);
            t2 = fmaxf(t2, fminf(v, t1));
            if (v > t1) { t1 = v; i1 = gidx; }
        }

        if ((ct & 15) == 15) {                 // codebook boundary
            const int cbi = ct >> 4;
            const float o1 = __shfl_xor(t1, 32, 64);
            const float o2 = __shfl_xor(t2, 32, 64);
            const int   oi = __shfl_xor(i1, 32, 64);
            const float m2 = fmaxf(fmaxf(t2, o2), fminf(t1, o1));
            if (o1 > t1 || (o1 == t1 && oi < i1)) { t1 = o1; i1 = oi; }
            const bool unc = (t1 - m2) < MARGIN;
            if (lane < 32 && !unc)
                out[(size_t)row * NCB + cbi] = i1 - cbi * MCODES;

            unsigned long long msk = __ballot(unc && lane < 32);
            while (msk) {                      // rare exact-f32 recheck
                const int r = __ffsll(msk) - 1; msk &= msk - 1;
                const int grow = blockIdx.x * 128 + wv * 32 + r;
                const float* xr = xw + (size_t)grow * DEMB;
                float best = -INFINITY; int bi2 = 0;
#pragma unroll 1
                for (int j = 0; j < 8; ++j) {
                    const int c = lane + 64 * j;
                    const float* cv = cbn + ((size_t)cbi * MCODES + c) * DEMB;
                    float s0 = 0, s1 = 0, s2 = 0, s3 = 0;
#pragma unroll
                    for (int k = 0; k < DEMB; k += 4) {
                        const float4 xk = ld4(xr + k);
                        const float4 ck = ld4(cv + k);
                        s0 = fmaf(xk.x, ck.x, s0); s1 = fmaf(xk.y, ck.y, s1);
                        s2 = fmaf(xk.z, ck.z, s2); s3 = fmaf(xk.w, ck.w, s3);
                    }
                    const float s = (s0 + s1) + (s2 + s3);
                    if (s > best) { best = s; bi2 = c; }
                }
#pragma unroll
                for (int mm = 1; mm < 64; mm <<= 1) {
                    const float ov = __shfl_xor(best, mm, 64);
                    const int   oc = __shfl_xor(bi2, mm, 64);
                    if (ov > best || (ov == best && oc < bi2)) { best = ov; bi2 = oc; }
                }
                if (lane == 0) out[(size_t)grow * NCB + cbi] = bi2;
            }
            t1 = -INFINITY; t2 = -INFINITY; i1 = 0;
        }

        asm volatile("" ::: "memory");
        __builtin_amdgcn_s_barrier();          // protect buf[bi] from next stage
        asm volatile("" ::: "memory");
    }
}

// ---------------------------------------------------------------------------
// Fallback (ws too small): round-3 fused kernel (proven, 2 MB ws).
// ---------------------------------------------------------------------------
__global__ __launch_bounds__(256) void fused_quantize_kernel(
        const float* __restrict__ inp, const float* __restrict__ proj,
        const float* __restrict__ cbn, const unsigned short* __restrict__ cbA,
        int* __restrict__ out) {
    __shared__ float sX[128][132];
    __shared__ float sRn[128];
    const int tid = threadIdx.x;
    const int tx = tid & 31, ty = tid >> 5;
    const int rowBase = blockIdx.x * 128;

#pragma unroll 1
    for (int p = 0; p < 2; ++p) {
        float acc1[8][4];
#pragma unroll
        for (int i = 0; i < 8; ++i)
#pragma unroll
            for (int j = 0; j < 4; ++j) acc1[i][j] = 0.0f;
        const float* inRow0 = inp + (size_t)(rowBase + p * 64 + ty) * DIN;
        const float* pjCol  = proj + tx * 4;
        float4 ivA[8], ivB[8], pjA[4], pjB[4];
        auto load_step = [&](float4 iv[8], float4 pj[4], int kk) {
#pragma unroll
            for (int j = 0; j < 4; ++j) pj[j] = ld4(pjCol + (size_t)(kk + j) * DEMB);
#pragma unroll
            for (int i = 0; i < 8; ++i) iv[i] = ld4(inRow0 + (size_t)(8 * i) * DIN + kk);
        };
        auto fma_step = [&](const float4 iv[8], const float4 pj[4]) {
#pragma unroll
            for (int i = 0; i < 8; ++i) {
                const float* ivp = reinterpret_cast<const float*>(&iv[i]);
#pragma unroll
                for (int j = 0; j < 4; ++j) {
                    acc1[i][0] = fmaf(ivp[j], pj[j].x, acc1[i][0]);
                    acc1[i][1] = fmaf(ivp[j], pj[j].y, acc1[i][1]);
                    acc1[i][2] = fmaf(ivp[j], pj[j].z, acc1[i][2]);
                    acc1[i][3] = fmaf(ivp[j], pj[j].w, acc1[i][3]);
                }
            }
        };
        load_step(ivA, pjA, 0);
#pragma unroll 1
        for (int k = 0; k < DIN; k += 8) {
            load_step(ivB, pjB, k + 4);
            fma_step(ivA, pjA);
            if (k + 8 < DIN) load_step(ivA, pjA, k + 8);
            fma_step(ivB, pjB);
        }
#pragma unroll
        for (int i = 0; i < 8; ++i) {
            const int r = p * 64 + ty + 8 * i;
            float ss = acc1[i][0] * acc1[i][0] + acc1[i][1] * acc1[i][1] +
                       acc1[i][2] * acc1[i][2] + acc1[i][3] * acc1[i][3];
#pragma unroll
            for (int mm = 1; mm < 32; mm <<= 1) ss += __shfl_xor(ss, mm, 64);
            if (tx == 0) sRn[r] = 1.0f / sqrtf(ss);
            *reinterpret_cast<float4*>(&sX[r][tx * 4]) =
                make_float4(acc1[i][0], acc1[i][1], acc1[i][2], acc1[i][3]);
        }
    }
    __syncthreads();

    const int lane = tid & 63, wv = tid >> 6;
    const int kg = lane >> 5;
    const int rowL = wv * 32 + (lane & 31);
    bf16x8 Bhi[8], Blo[8];
    {
        const float rn = sRn[rowL];
#pragma unroll
        for (int kt = 0; kt < 8; ++kt) {
            const int k0 = kt * 16 + kg * 8;
            float4 f0 = ld4(&sX[rowL][k0]);
            float4 f1 = ld4(&sX[rowL][k0 + 4]);
            float xs[8] = {f0.x, f0.y, f0.z, f0.w, f1.x, f1.y, f1.z, f1.w};
            bf16x8 hv, lv;
#pragma unroll
            for (int e = 0; e < 8; ++e) {
                const float xn = xs[e] * rn;
                const unsigned short h = f2bf(xn);
                hv[e] = (short)h;
                lv[e] = (short)f2bf(xn - bf2f(h));
            }
            Bhi[kt] = hv; Blo[kt] = lv;
        }
    }
    float t1 = -INFINITY, t2 = -INFINITY; int i1 = 0;
    const short* pA = reinterpret_cast<const short*>(cbA) + (size_t)lane * 8;
#pragma unroll 1
    for (int ct = 0; ct < 64; ++ct) {
        if ((ct & 1) == 0) __syncthreads();
        const short* pct = pA + (size_t)ct * 8192;
        f32x16 accA, accB;
#pragma unroll
        for (int r = 0; r < 16; ++r) { accA[r] = 0.0f; accB[r] = 0.0f; }
#pragma unroll
        for (int kt = 0; kt < 8; ++kt) {
            const bf16x8 Ahi = *reinterpret_cast<const bf16x8*>(pct + kt * 1024);
            const bf16x8 Alo = *reinterpret_cast<const bf16x8*>(pct + kt * 1024 + 512);
            accA = __builtin_amdgcn_mfma_f32_32x32x16_bf16(Ahi, Bhi[kt], accA, 0, 0, 0);
            accB = __builtin_amdgcn_mfma_f32_32x32x16_bf16(Ahi, Blo[kt], accB, 0, 0, 0);
            accB = __builtin_amdgcn_mfma_f32_32x32x16_bf16(Alo, Bhi[kt], accB, 0, 0, 0);
        }
#pragma unroll
        for (int r = 0; r < 16; ++r) {
            const float v = accA[r] + accB[r];
            const int gidx = ct * 32 + ((r & 3) + 8 * (r >> 2) + 4 * kg);
            t2 = fmaxf(t2, fminf(v, t1));
            if (v > t1) { t1 = v; i1 = gidx; }
        }
        if ((ct & 15) == 15) {
            const int cbi = ct >> 4;
            const float o1 = __shfl_xor(t1, 32, 64);
            const float o2 = __shfl_xor(t2, 32, 64);
            const int   oi = __shfl_xor(i1, 32, 64);
            const float m2 = fmaxf(fmaxf(t2, o2), fminf(t1, o1));
            if (o1 > t1 || (o1 == t1 && oi < i1)) { t1 = o1; i1 = oi; }
            const bool unc = (t1 - m2) < MARGIN;
            if (lane < 32 && !unc)
                out[(size_t)(rowBase + rowL) * NCB + cbi] = i1 - cbi * MCODES;
            unsigned long long msk = __ballot(unc && lane < 32);
            while (msk) {
                const int r = __ffsll(msk) - 1; msk &= msk - 1;
                const int rl = wv * 32 + r;
                float best = -INFINITY; int bi = 0;
#pragma unroll 1
                for (int j = 0; j < 8; ++j) {
                    const int c = lane + 64 * j;
                    const float* cv = cbn + ((size_t)cbi * MCODES + c) * DEMB;
                    float s0 = 0, s1 = 0, s2 = 0, s3 = 0;
#pragma unroll
                    for (int k = 0; k < DEMB; k += 4) {
                        const float4 xk = ld4(&sX[rl][k]);
                        const float4 ck = ld4(cv + k);
                        s0 = fmaf(xk.x, ck.x, s0); s1 = fmaf(xk.y, ck.y, s1);
                        s2 = fmaf(xk.z, ck.z, s2); s3 = fmaf(xk.w, ck.w, s3);
                    }
                    const float s = (s0 + s1) + (s2 + s3);
                    if (s > best) { best = s; bi = c; }
                }
#pragma unroll
                for (int mm = 1; mm < 64; mm <<= 1) {
                    const float ov = __shfl_xor(best, mm, 64);
                    const int   oc = __shfl_xor(bi, mm, 64);
                    if (ov > best || (ov == best && oc < bi)) { best = ov; bi = oc; }
                }
                if (lane == 0) out[(size_t)(rowBase + rl) * NCB + cbi] = bi;
            }
            t1 = -INFINITY; t2 = -INFINITY; i1 = 0;
        }
    }
}

// ---------------------------------------------------------------------------
extern "C" void kernel_launch(void* const* d_in, const int* in_sizes, int n_in,
                              void* d_out, int out_size, void* d_ws, size_t ws_size,
                              hipStream_t stream) {
    const float* inp  = (const float*)d_in[0];   // [8,16,512,256]
    const float* proj = (const float*)d_in[1];   // [256,128]
    const float* cb   = (const float*)d_in[2];   // [4,512,128]
    int* out = (int*)d_out;                      // [8,16,512,4] int32

    char* ws = (char*)d_ws;
    float* cbn = (float*)ws;                               // 1 MB
    unsigned short* cbA = (unsigned short*)(ws + (1 << 20)); // 1 MB
    float* rnw = (float*)(ws + (2 << 20));                 // 256 KB
    float* xw  = (float*)(ws + (2 << 20) + (1 << 18));     // 32 MB
    const size_t need = (size_t)(2 << 20) + (1 << 18) + (size_t)65536 * DEMB * 4;

    hipLaunchKernelGGL(prep_codebook, dim3(NCODE / 4), dim3(256), 0, stream,
                       cb, cbn, cbA);
    if (ws_size >= need) {
        hipLaunchKernelGGL(project_kernel, dim3(1024), dim3(256), 0, stream,
                           inp, proj, xw, rnw);
        hipLaunchKernelGGL(sim_kernel, dim3(512), dim3(256), 0, stream,
                           xw, rnw, cbA, cbn, out);
    } else {
        hipLaunchKernelGGL(fused_quantize_kernel, dim3(512), dim3(256), 0, stream,
                           inp, proj, cbn, cbA, out);
    }
}